// Round 1
// baseline (73.970 us; speedup 1.0000x reference)
//
#include <hip/hip_runtime.h>

// L0ConjunctionLayer eval forward (fuzzy-AND):
//   z[i]     = clip(sigmoid(qz[i]) * 1.2 - 0.1, 0, 1)
//   out[b,o] = prod_i (1 - (1 - x[b,i]) * z[i] * W[i,o])
// B=64, I=1024, O=1024, fp32.
//
// SINGLE fused kernel, NO workspace, ONE launch.
// grid = (16 batch-groups, 32 output-chunks) = 512 blocks x 256 threads
// (2 blocks/CU -> 2 waves/SIMD for latency hiding).
// Thread t: bb = t>>6 (batch within group), h = (t>>5)&1 (i-half),
//           ol = t&31 (output within chunk).
// Each thread folds its 512-long i-half into 4 interleaved product chains
// (breaks the dependent-mul latency chain), then the two halves are
// combined with a single __shfl_xor(acc, 32) multiply -- no global
// partials, no combine kernel.
#define BATCH 64
#define IN_F  1024
#define OUT_F 1024

__global__ __launch_bounds__(256) void l0_fuzzy_and_fused(
        const float* __restrict__ x,
        const float* __restrict__ w,
        const float* __restrict__ qz,
        float* __restrict__ outp)
{
    __shared__ float u_lds[4 * IN_F];   // [bb][i] = (1 - x[b][i]) * z[i], 16 KB

    const int b0 = blockIdx.x * 4;      // batch group
    const int oc = blockIdx.y;          // output chunk (32 outputs)
    const int t  = threadIdx.x;

    // Stage u = (1-x)*z. 1024 i's over 256 threads -> 4 iters; z computed
    // once per i (not 4x). Coalesced x loads, conflict-free LDS writes.
    for (int ii = t; ii < IN_F; ii += 256) {
        const float q  = qz[ii];
        const float pi = 1.0f / (1.0f + expf(-q));
        float z = fmaf(pi, 1.2f, -0.1f);
        z = fminf(fmaxf(z, 0.0f), 1.0f);
#pragma unroll
        for (int bb = 0; bb < 4; ++bb)
            u_lds[bb * IN_F + ii] = (1.0f - x[(b0 + bb) * IN_F + ii]) * z;
    }
    __syncthreads();

    const int ol = t & 31;
    const int h  = (t >> 5) & 1;        // which 512-long half of i
    const int bb = t >> 6;
    const int o  = oc * 32 + ol;

    // W walk: lanes 0-31 read row i, lanes 32-63 read row i+512 -> two
    // contiguous 128B segments per wave load. u reads: wave-uniform per
    // half-wave -> 2-address LDS broadcast (2-way aliasing = free).
    const float* wp = w + (size_t)h * (IN_F / 2) * OUT_F + o;
    const float* up = u_lds + bb * IN_F + h * (IN_F / 2);

    float a0 = 1.0f, a1 = 1.0f, a2 = 1.0f, a3 = 1.0f;
#pragma unroll 4
    for (int i = 0; i < IN_F / 2; i += 8) {
        const float4 ua = *(const float4*)(up + i);
        const float4 ub = *(const float4*)(up + i + 4);
        const float w0 = wp[(size_t)(i + 0) * OUT_F];
        const float w1 = wp[(size_t)(i + 1) * OUT_F];
        const float w2 = wp[(size_t)(i + 2) * OUT_F];
        const float w3 = wp[(size_t)(i + 3) * OUT_F];
        const float w4 = wp[(size_t)(i + 4) * OUT_F];
        const float w5 = wp[(size_t)(i + 5) * OUT_F];
        const float w6 = wp[(size_t)(i + 6) * OUT_F];
        const float w7 = wp[(size_t)(i + 7) * OUT_F];
        a0 *= fmaf(-ua.x, w0, 1.0f);    // *(1 - u*w)
        a1 *= fmaf(-ua.y, w1, 1.0f);
        a2 *= fmaf(-ua.z, w2, 1.0f);
        a3 *= fmaf(-ua.w, w3, 1.0f);
        a0 *= fmaf(-ub.x, w4, 1.0f);
        a1 *= fmaf(-ub.y, w5, 1.0f);
        a2 *= fmaf(-ub.z, w6, 1.0f);
        a3 *= fmaf(-ub.w, w7, 1.0f);
    }

    float acc = (a0 * a1) * (a2 * a3);
    acc *= __shfl_xor(acc, 32);         // combine the two i-halves in-wave
    if (h == 0)
        outp[(size_t)(b0 + bb) * OUT_F + o] = acc;
}

extern "C" void kernel_launch(void* const* d_in, const int* in_sizes, int n_in,
                              void* d_out, int out_size, void* d_ws, size_t ws_size,
                              hipStream_t stream)
{
    const float* x  = (const float*)d_in[0];   // (64, 1024)
    const float* w  = (const float*)d_in[1];   // (1024, 1024)
    const float* qz = (const float*)d_in[2];   // (1024,)
    (void)d_ws; (void)ws_size;                 // deliberately unused

    hipLaunchKernelGGL(l0_fuzzy_and_fused, dim3(BATCH / 4, OUT_F / 32),
                       dim3(256), 0, stream, x, w, qz, (float*)d_out);
}